// Round 6
// baseline (205.542 us; speedup 1.0000x reference)
//
#include <hip/hip_runtime.h>
#include <hip/hip_bf16.h>
#include <stdint.h>

#define NSEQ 4096
#define DDIM 512
#define NB   8

#define BMN 256
#define BK  64
#define NT  (NSEQ / BK)   // 64 K-tiles

typedef float f32x16 __attribute__((ext_vector_type(16)));
typedef __bf16 bf16x8 __attribute__((ext_vector_type(8)));

typedef const void __attribute__((address_space(1))) gvoid_t;
typedef void __attribute__((address_space(3))) svoid_t;

#define SBAR() do { __builtin_amdgcn_s_barrier(); asm volatile("" ::: "memory"); } while (0)

__device__ __forceinline__ unsigned short f2bf(float f) {
    union { float f; unsigned int u; } v;
    v.f = f;
    unsigned int u = v.u;
    u += 0x7FFFu + ((u >> 16) & 1u);   // RNE
    return (unsigned short)(u >> 16);
}

// ---------------------------------------------------------------------------
// Kernel 1: T[i][j] = bf16(exp(clamp(w(i-j))))
// ---------------------------------------------------------------------------
__global__ void build_T(const float* __restrict__ pos,
                        const float* __restrict__ zero,
                        const float* __restrict__ neg,
                        unsigned short* __restrict__ T) {
    int tid = blockIdx.x * blockDim.x + threadIdx.x;
    int i  = tid >> 9;
    int j0 = (tid & 511) << 3;
    float z = zero[0];
    unsigned short r[8];
#pragma unroll
    for (int e = 0; e < 8; ++e) {
        int j = j0 + e;
        int d = i - j;
        float v;
        if (d > 0)       v = pos[d - 1];
        else if (d == 0) v = z;
        else             v = neg[NSEQ - 1 + d];
        v = fminf(fmaxf(v, -60.0f), 30.0f);
        r[e] = f2bf(__expf(v));
    }
    uint4 o;
    o.x = (unsigned int)r[0] | ((unsigned int)r[1] << 16);
    o.y = (unsigned int)r[2] | ((unsigned int)r[3] << 16);
    o.z = (unsigned int)r[4] | ((unsigned int)r[5] << 16);
    o.w = (unsigned int)r[6] | ((unsigned int)r[7] << 16);
    *(uint4*)(T + (size_t)i * NSEQ + j0) = o;
}

// ---------------------------------------------------------------------------
// Kernel 2: xT[b][d][j] = bf16(x[b][j][d])
// ---------------------------------------------------------------------------
__global__ void transpose_x(const float* __restrict__ x,
                            unsigned short* __restrict__ xT) {
    __shared__ unsigned short tile[64][66];
    int b  = blockIdx.z;
    int j0 = blockIdx.x * 64;
    int d0 = blockIdx.y * 64;
    const float* xb = x + (size_t)b * NSEQ * DDIM;
#pragma unroll
    for (int e = 0; e < 16; ++e) {
        int idx = e * 256 + threadIdx.x;
        int r = idx >> 6, c = idx & 63;
        tile[r][c] = f2bf(xb[(size_t)(j0 + r) * DDIM + d0 + c]);
    }
    __syncthreads();
    unsigned short* xtb = xT + (size_t)b * DDIM * NSEQ;
#pragma unroll
    for (int e = 0; e < 16; ++e) {
        int idx = e * 256 + threadIdx.x;
        int r = idx >> 6, c = idx & 63;
        xtb[(size_t)(d0 + r) * NSEQ + j0 + c] = tile[c][r];
    }
}

// ---------------------------------------------------------------------------
// Kernel 3: out[b] = T @ x[b], 32x32x16 MFMA + Toeplitz A-register-ring +
// cross-tile pipelined B-reads.  256x256x64 tiles, 8 waves (2M x 4N).
// Per tile: Q3 Q2 | stage(kt+2), vmcnt(5), SBAR | read B(kt+1)+freshA(kt+1)
// interleaved with Q1 Q0.  ONE barrier, one vmcnt, one lgkmcnt per tile.
// bfr double-buffered (static ping-pong via 6-tile unroll).
// ---------------------------------------------------------------------------
__global__ __launch_bounds__(512, 2) void gemm_toep32p(
        const unsigned short* __restrict__ T,    // [NSEQ][NSEQ] bf16
        const unsigned short* __restrict__ xT,   // [NB][DDIM][NSEQ] bf16
        float* __restrict__ out) {               // [NB][NSEQ][DDIM] f32
    __shared__ __attribute__((aligned(16))) unsigned short sA[3][64 * BK];   // 8 KB x3
    __shared__ __attribute__((aligned(16))) unsigned short sB[3][BMN * BK];  // 32 KB x3

    const int tid  = threadIdx.x;
    const int lane = tid & 63;
    const int wid  = tid >> 6;      // 0..7
    const int wm   = wid >> 2;      // 0..1 -> 128-row half
    const int wn   = wid & 3;       // 0..3 -> 64-col quarter
    const int l31  = lane & 31;
    const int lhi2 = lane >> 5;     // 0..1

    // ---- XCD-aware bijective block swizzle (256 blocks, 8 XCDs) ----
    int lin = blockIdx.x;
    int swz = (lin & 7) * 32 + (lin >> 3);
    int it  = swz >> 4;
    int tn  = (swz & 15) & 1;
    int b   = (swz & 15) >> 1;
    const int i0 = it * BMN;
    const int n0 = tn * BMN;

    const unsigned short* Ag = T + (size_t)i0 * NSEQ;
    const unsigned short* Bg = xT + ((size_t)b * DDIM + n0) * NSEQ;

    // staging geometry: 8 rows x 128B per instr, pre-swizzled source chunk
    const int srow = lane >> 3;
    const int schk = (lane & 7) ^ srow;
    const int agrow = (wid < 4) ? (wid * 8 + srow) : (128 + (wid - 4) * 8 + srow);
    const uint32_t offA = (uint32_t)agrow * NSEQ + schk * 8;
    uint32_t offB[4];
#pragma unroll
    for (int q = 0; q < 4; ++q)
        offB[q] = (uint32_t)((q * 8 + wid) * 8 + srow) * NSEQ + schk * 8;

#define STAGE(BUF, K0) do { \
    __builtin_amdgcn_global_load_lds( \
        (gvoid_t*)(const void*)(Ag + offA + (K0)), \
        (svoid_t*)(void*)(&sA[BUF][0] + wid * 512), 16, 0, 0); \
    _Pragma("unroll") \
    for (int q_ = 0; q_ < 4; ++q_) \
        __builtin_amdgcn_global_load_lds( \
            (gvoid_t*)(const void*)(Bg + offB[q_] + (K0)), \
            (svoid_t*)(void*)(&sB[BUF][0] + (q_ * 8 + wid) * 512), 16, 0, 0); \
} while (0)

    f32x16 acc[4][2];
#pragma unroll
    for (int m = 0; m < 4; ++m)
#pragma unroll
        for (int n = 0; n < 2; ++n)
#pragma unroll
            for (int r = 0; r < 16; ++r)
                acc[m][n][r] = 0.f;

    // ---- A-frag ring init for tile 0 (slots 0..9 = key16 -3..6) ----
    bf16x8 af[12];
#pragma unroll
    for (int kb = -3; kb <= 6; ++kb) {
        int mt = (kb <= 0) ? 0 : ((kb + 1) >> 1);
        int kk = 2 * mt - kb;
        af[kb + 3] = *(const bf16x8*)(T +
            (size_t)(i0 + wm * 128 + mt * 32 + l31) * NSEQ + kk * 16 + lhi2 * 8);
    }

    bf16x8 bfr[2][2][4];

#define READB(PPN, KTMN) { \
    const unsigned short* Bs_ = &sB[KTMN][0]; \
    _Pragma("unroll") \
    for (int n_ = 0; n_ < 2; ++n_) { \
        int row_ = wn * 64 + n_ * 32 + l31; \
        int rb_ = row_ * BK, rx_ = row_ & 7; \
        _Pragma("unroll") \
        for (int kk_ = 0; kk_ < 4; ++kk_) \
            bfr[PPN][n_][kk_] = *(const bf16x8*)&Bs_[rb_ + (((kk_ * 2 + lhi2) ^ rx_) << 3)]; \
    } }

    STAGE(0, 0);
    STAGE(1, BK);
    asm volatile("s_waitcnt vmcnt(0)" ::: "memory");
    SBAR();
    READB(0, 0)   // B(0) into bfr[0]

// slot of frag (mt,kk) in tile with kt%3==KTM  (compile-time under unroll)
#define SLOT(MT, KK, KTM) (((2 * (MT) - (KK) - 4 * (KTM) + 3) % 12 + 12) % 12)
// slot of fresh frag j (= (mt0, kk=3-j) of tile kt+1), written in body kt
#define FSLOT(J, KTM) ((((J) - 4 * (((KTM) + 1) % 3)) % 12 + 12) % 12)

#define QC(MT, KTM, PP) \
    _Pragma("unroll") \
    for (int n_ = 0; n_ < 2; ++n_) \
      _Pragma("unroll") \
      for (int kk_ = 0; kk_ < 4; ++kk_) \
        acc[MT][n_] = __builtin_amdgcn_mfma_f32_32x32x16_bf16( \
            af[SLOT(MT, kk_, KTM)], bfr[PP][n_][kk_], acc[MT][n_], 0, 0, 0);

#define TILE_BODY(KTM, PP, KT, DOSTAGE, DONEXTB, DOFRESH) { \
    asm volatile("s_waitcnt lgkmcnt(0)" ::: "memory"); \
    __builtin_amdgcn_sched_barrier(0); \
    __builtin_amdgcn_s_setprio(1); \
    QC(3, KTM, PP) \
    QC(2, KTM, PP) \
    __builtin_amdgcn_s_setprio(0); \
    if (DOSTAGE) { \
        STAGE((((KTM) + 2) % 3), ((KT) + 2) * BK); \
        asm volatile("s_waitcnt vmcnt(5)" ::: "memory"); \
    } else { \
        asm volatile("s_waitcnt vmcnt(0)" ::: "memory"); \
    } \
    SBAR(); \
    if (DONEXTB) READB((PP) ^ 1, (((KTM) + 1) % 3)) \
    if (DOFRESH) { \
        const unsigned short* An = &sA[((KTM) + 1) % 3][0]; \
        int row_ = wm * 32 + l31; \
        int rb_ = row_ * 64, rx_ = row_ & 7; \
        af[FSLOT(0, KTM)] = *(const bf16x8*)&An[rb_ + (((3 * 2 + lhi2) ^ rx_) << 3)]; \
        af[FSLOT(1, KTM)] = *(const bf16x8*)&An[rb_ + (((2 * 2 + lhi2) ^ rx_) << 3)]; \
        af[FSLOT(2, KTM)] = *(const bf16x8*)&An[rb_ + (((1 * 2 + lhi2) ^ rx_) << 3)]; \
        af[FSLOT(3, KTM)] = *(const bf16x8*)&An[rb_ + (((0 * 2 + lhi2) ^ rx_) << 3)]; \
    } \
    __builtin_amdgcn_s_setprio(1); \
    QC(1, KTM, PP) \
    QC(0, KTM, PP) \
    __builtin_amdgcn_s_setprio(0); \
}

    for (int s = 0; s < 10; ++s) {
        const int kt = s * 6;
        TILE_BODY(0, 0, (kt + 0), 1, 1, 1)
        TILE_BODY(1, 1, (kt + 1), 1, 1, 1)
        TILE_BODY(2, 0, (kt + 2), 1, 1, 1)
        TILE_BODY(0, 1, (kt + 3), 1, 1, 1)
        TILE_BODY(1, 0, (kt + 4), 1, 1, 1)
        TILE_BODY(2, 1, (kt + 5), 1, 1, 1)
    }
    TILE_BODY(0, 0, 60, 1, 1, 1)
    TILE_BODY(1, 1, 61, 1, 1, 1)
    TILE_BODY(2, 0, 62, 0, 1, 1)
    TILE_BODY(0, 1, 63, 0, 0, 0)

#undef TILE_BODY
#undef QC
#undef SLOT
#undef FSLOT
#undef STAGE
#undef READB

    // ---- epilogue: 32x32 C/D layout col=lane&31, row=(reg&3)+8*(reg>>2)+4*(lane>>5)
    float* outb = out + ((size_t)b * NSEQ + i0 + wm * 128) * DDIM + n0 + wn * 64;
#pragma unroll
    for (int mt = 0; mt < 4; ++mt)
#pragma unroll
        for (int n = 0; n < 2; ++n)
#pragma unroll
            for (int r = 0; r < 16; ++r) {
                int row = mt * 32 + (r & 3) + 8 * (r >> 2) + 4 * lhi2;
                outb[(size_t)row * DDIM + n * 32 + l31] = acc[mt][n][r];
            }
}

// ---------------------------------------------------------------------------
extern "C" void kernel_launch(void* const* d_in, const int* in_sizes, int n_in,
                              void* d_out, int out_size, void* d_ws, size_t ws_size,
                              hipStream_t stream) {
    const float* x    = (const float*)d_in[0];
    const float* pos  = (const float*)d_in[1];
    const float* zero = (const float*)d_in[2];
    const float* neg  = (const float*)d_in[3];
    float* out = (float*)d_out;

    unsigned short* Tm = (unsigned short*)d_ws;                    // 32 MiB
    unsigned short* xT = Tm + (size_t)NSEQ * NSEQ;                 // 32 MiB

    build_T<<<dim3(NSEQ * NSEQ / 8 / 256), 256, 0, stream>>>(pos, zero, neg, Tm);
    transpose_x<<<dim3(NSEQ / 64, DDIM / 64, NB), 256, 0, stream>>>(x, xT);
    gemm_toep32p<<<dim3(NSEQ / BMN * (DDIM / BMN) * NB), 512, 0, stream>>>(Tm, xT, out);
}

// Round 7
// 161.826 us; speedup vs baseline: 1.2701x; 1.2701x over previous
//
#include <hip/hip_runtime.h>
#include <hip/hip_bf16.h>
#include <stdint.h>

#define NSEQ 4096
#define DDIM 512
#define NB   8

#define BMN 256
#define BK  64
#define NT  (NSEQ / BK)   // 64 K-tiles

typedef float f32x16 __attribute__((ext_vector_type(16)));
typedef __bf16 bf16x8 __attribute__((ext_vector_type(8)));

typedef const void __attribute__((address_space(1))) gvoid_t;
typedef void __attribute__((address_space(3))) svoid_t;

#define SBAR() do { __builtin_amdgcn_s_barrier(); asm volatile("" ::: "memory"); } while (0)

__device__ __forceinline__ unsigned short f2bf(float f) {
    union { float f; unsigned int u; } v;
    v.f = f;
    unsigned int u = v.u;
    u += 0x7FFFu + ((u >> 16) & 1u);   // RNE
    return (unsigned short)(u >> 16);
}

// ---------------------------------------------------------------------------
// Kernel 1: T[i][j] = bf16(exp(clamp(w(i-j))))
// ---------------------------------------------------------------------------
__global__ void build_T(const float* __restrict__ pos,
                        const float* __restrict__ zero,
                        const float* __restrict__ neg,
                        unsigned short* __restrict__ T) {
    int tid = blockIdx.x * blockDim.x + threadIdx.x;
    int i  = tid >> 9;
    int j0 = (tid & 511) << 3;
    float z = zero[0];
    unsigned short r[8];
#pragma unroll
    for (int e = 0; e < 8; ++e) {
        int j = j0 + e;
        int d = i - j;
        float v;
        if (d > 0)       v = pos[d - 1];
        else if (d == 0) v = z;
        else             v = neg[NSEQ - 1 + d];
        v = fminf(fmaxf(v, -60.0f), 30.0f);
        r[e] = f2bf(__expf(v));
    }
    uint4 o;
    o.x = (unsigned int)r[0] | ((unsigned int)r[1] << 16);
    o.y = (unsigned int)r[2] | ((unsigned int)r[3] << 16);
    o.z = (unsigned int)r[4] | ((unsigned int)r[5] << 16);
    o.w = (unsigned int)r[6] | ((unsigned int)r[7] << 16);
    *(uint4*)(T + (size_t)i * NSEQ + j0) = o;
}

// ---------------------------------------------------------------------------
// Kernel 2: xT[b][d][j] = bf16(x[b][j][d])
// ---------------------------------------------------------------------------
__global__ void transpose_x(const float* __restrict__ x,
                            unsigned short* __restrict__ xT) {
    __shared__ unsigned short tile[64][66];
    int b  = blockIdx.z;
    int j0 = blockIdx.x * 64;
    int d0 = blockIdx.y * 64;
    const float* xb = x + (size_t)b * NSEQ * DDIM;
#pragma unroll
    for (int e = 0; e < 16; ++e) {
        int idx = e * 256 + threadIdx.x;
        int r = idx >> 6, c = idx & 63;
        tile[r][c] = f2bf(xb[(size_t)(j0 + r) * DDIM + d0 + c]);
    }
    __syncthreads();
    unsigned short* xtb = xT + (size_t)b * DDIM * NSEQ;
#pragma unroll
    for (int e = 0; e < 16; ++e) {
        int idx = e * 256 + threadIdx.x;
        int r = idx >> 6, c = idx & 63;
        xtb[(size_t)(d0 + r) * NSEQ + j0 + c] = tile[c][r];
    }
}

// ---------------------------------------------------------------------------
// Kernel 3: out[b] = T @ x[b], 32x32x16 MFMA + Toeplitz A-register-ring +
// n-half-split cross-tile pipelined B-reads (register-neutral: bfr0/bfr1,
// 16 VGPR each, no double-buffer).  Per tile:
//   lgkm0 | issue bfr1 | Q(n0) 16 MFMA | STAGE,vmcnt(5) | lgkm0,SBAR |
//   Q(n1,mt3) | issue next bfr0 + freshA | Q(n1,mt2..0)
// All LDS reads overlap MFMA; one barrier/tile; vmcnt never 0 in steady state.
// ---------------------------------------------------------------------------
__global__ __launch_bounds__(512, 2) void gemm_toep32n(
        const unsigned short* __restrict__ T,    // [NSEQ][NSEQ] bf16
        const unsigned short* __restrict__ xT,   // [NB][DDIM][NSEQ] bf16
        float* __restrict__ out) {               // [NB][NSEQ][DDIM] f32
    __shared__ __attribute__((aligned(16))) unsigned short sA[3][64 * BK];   // 8 KB x3
    __shared__ __attribute__((aligned(16))) unsigned short sB[3][BMN * BK];  // 32 KB x3

    const int tid  = threadIdx.x;
    const int lane = tid & 63;
    const int wid  = tid >> 6;      // 0..7
    const int wm   = wid >> 2;      // 0..1 -> 128-row half
    const int wn   = wid & 3;       // 0..3 -> 64-col quarter
    const int l31  = lane & 31;
    const int lhi2 = lane >> 5;     // 0..1

    // ---- XCD-aware bijective block swizzle (256 blocks, 8 XCDs) ----
    int lin = blockIdx.x;
    int swz = (lin & 7) * 32 + (lin >> 3);
    int it  = swz >> 4;
    int tn  = (swz & 15) & 1;
    int b   = (swz & 15) >> 1;
    const int i0 = it * BMN;
    const int n0 = tn * BMN;

    const unsigned short* Ag = T + (size_t)i0 * NSEQ;
    const unsigned short* Bg = xT + ((size_t)b * DDIM + n0) * NSEQ;

    // staging geometry: 8 rows x 128B per instr, pre-swizzled source chunk
    const int srow = lane >> 3;
    const int schk = (lane & 7) ^ srow;
    const int agrow = (wid < 4) ? (wid * 8 + srow) : (128 + (wid - 4) * 8 + srow);
    const uint32_t offA = (uint32_t)agrow * NSEQ + schk * 8;
    uint32_t offB[4];
#pragma unroll
    for (int q = 0; q < 4; ++q)
        offB[q] = (uint32_t)((q * 8 + wid) * 8 + srow) * NSEQ + schk * 8;

#define STAGE(BUF, K0) do { \
    __builtin_amdgcn_global_load_lds( \
        (gvoid_t*)(const void*)(Ag + offA + (K0)), \
        (svoid_t*)(void*)(&sA[BUF][0] + wid * 512), 16, 0, 0); \
    _Pragma("unroll") \
    for (int q_ = 0; q_ < 4; ++q_) \
        __builtin_amdgcn_global_load_lds( \
            (gvoid_t*)(const void*)(Bg + offB[q_] + (K0)), \
            (svoid_t*)(void*)(&sB[BUF][0] + (q_ * 8 + wid) * 512), 16, 0, 0); \
} while (0)

    f32x16 acc[4][2];
#pragma unroll
    for (int m = 0; m < 4; ++m)
#pragma unroll
        for (int n = 0; n < 2; ++n)
#pragma unroll
            for (int r = 0; r < 16; ++r)
                acc[m][n][r] = 0.f;

    // ---- A-frag ring init for tile 0 (slots 0..9 = key16 -3..6) ----
    bf16x8 af[12];
#pragma unroll
    for (int kb = -3; kb <= 6; ++kb) {
        int mt = (kb <= 0) ? 0 : ((kb + 1) >> 1);
        int kk = 2 * mt - kb;
        af[kb + 3] = *(const bf16x8*)(T +
            (size_t)(i0 + wm * 128 + mt * 32 + l31) * NSEQ + kk * 16 + lhi2 * 8);
    }

    bf16x8 bfr0[4], bfr1[4];

// read B fragments for n-half H of buffer BUF into BF (4 x ds_read_b128)
#define READB(BF, BUF, H) { \
    const unsigned short* Bs_ = &sB[BUF][0]; \
    int row_ = wn * 64 + (H) * 32 + l31; \
    int rb_ = row_ * BK, rx_ = row_ & 7; \
    _Pragma("unroll") \
    for (int kk_ = 0; kk_ < 4; ++kk_) \
        BF[kk_] = *(const bf16x8*)&Bs_[rb_ + (((kk_ * 2 + lhi2) ^ rx_) << 3)]; \
}

    STAGE(0, 0);
    STAGE(1, BK);
    asm volatile("s_waitcnt vmcnt(5)" ::: "memory");
    SBAR();
    __builtin_amdgcn_sched_barrier(0);
    READB(bfr0, 0, 0)    // B(0, n=0)

// slot of frag (mt,kk) in tile with kt%3==KTM  (compile-time under unroll)
#define SLOT(MT, KK, KTM) (((2 * (MT) - (KK) - 4 * (KTM) + 3) % 12 + 12) % 12)
// slot of fresh frag j (= (mt0, kk=3-j) of tile kt+1), written in body kt
#define FSLOT(J, KTM) ((((J) - 4 * (((KTM) + 1) % 3)) % 12 + 12) % 12)

#define QCH(MT, KTM, BF, H) \
    _Pragma("unroll") \
    for (int kk_ = 0; kk_ < 4; ++kk_) \
        acc[MT][H] = __builtin_amdgcn_mfma_f32_32x32x16_bf16( \
            af[SLOT(MT, kk_, KTM)], BF[kk_], acc[MT][H], 0, 0, 0);

#define TILE_BODY(KTM, KT, DOSTAGE, DONEXT) { \
    asm volatile("s_waitcnt lgkmcnt(0)" ::: "memory"); \
    __builtin_amdgcn_sched_barrier(0); \
    READB(bfr1, KTM, 1) \
    __builtin_amdgcn_s_setprio(1); \
    QCH(3, KTM, bfr0, 0) \
    QCH(2, KTM, bfr0, 0) \
    QCH(1, KTM, bfr0, 0) \
    QCH(0, KTM, bfr0, 0) \
    __builtin_amdgcn_s_setprio(0); \
    if (DOSTAGE) { \
        STAGE((((KTM) + 2) % 3), ((KT) + 2) * BK); \
        asm volatile("s_waitcnt vmcnt(5)" ::: "memory"); \
    } else { \
        asm volatile("s_waitcnt vmcnt(0)" ::: "memory"); \
    } \
    asm volatile("s_waitcnt lgkmcnt(0)" ::: "memory"); \
    SBAR(); \
    __builtin_amdgcn_sched_barrier(0); \
    __builtin_amdgcn_s_setprio(1); \
    QCH(3, KTM, bfr1, 1) \
    __builtin_amdgcn_s_setprio(0); \
    if (DONEXT) { \
        READB(bfr0, (((KTM) + 1) % 3), 0) \
        const unsigned short* An = &sA[((KTM) + 1) % 3][0]; \
        int row_ = wm * 32 + l31; \
        int rb_ = row_ * 64, rx_ = row_ & 7; \
        af[FSLOT(0, KTM)] = *(const bf16x8*)&An[rb_ + (((3 * 2 + lhi2) ^ rx_) << 3)]; \
        af[FSLOT(1, KTM)] = *(const bf16x8*)&An[rb_ + (((2 * 2 + lhi2) ^ rx_) << 3)]; \
        af[FSLOT(2, KTM)] = *(const bf16x8*)&An[rb_ + (((1 * 2 + lhi2) ^ rx_) << 3)]; \
        af[FSLOT(3, KTM)] = *(const bf16x8*)&An[rb_ + (((0 * 2 + lhi2) ^ rx_) << 3)]; \
    } \
    __builtin_amdgcn_s_setprio(1); \
    QCH(2, KTM, bfr1, 1) \
    QCH(1, KTM, bfr1, 1) \
    QCH(0, KTM, bfr1, 1) \
    __builtin_amdgcn_s_setprio(0); \
}

    for (int s = 0; s < 20; ++s) {
        const int kt = s * 3;
        TILE_BODY(0, (kt + 0), 1, 1)
        TILE_BODY(1, (kt + 1), 1, 1)
        TILE_BODY(2, (kt + 2), 1, 1)
    }
    TILE_BODY(0, 60, 1, 1)
    TILE_BODY(1, 61, 1, 1)
    TILE_BODY(2, 62, 0, 1)
    TILE_BODY(0, 63, 0, 0)

#undef TILE_BODY
#undef QCH
#undef SLOT
#undef FSLOT
#undef STAGE
#undef READB

    // ---- epilogue: 32x32 C/D layout col=lane&31, row=(reg&3)+8*(reg>>2)+4*(lane>>5)
    float* outb = out + ((size_t)b * NSEQ + i0 + wm * 128) * DDIM + n0 + wn * 64;
#pragma unroll
    for (int mt = 0; mt < 4; ++mt)
#pragma unroll
        for (int n = 0; n < 2; ++n)
#pragma unroll
            for (int r = 0; r < 16; ++r) {
                int row = mt * 32 + (r & 3) + 8 * (r >> 2) + 4 * lhi2;
                outb[(size_t)row * DDIM + n * 32 + l31] = acc[mt][n][r];
            }
}

// ---------------------------------------------------------------------------
extern "C" void kernel_launch(void* const* d_in, const int* in_sizes, int n_in,
                              void* d_out, int out_size, void* d_ws, size_t ws_size,
                              hipStream_t stream) {
    const float* x    = (const float*)d_in[0];
    const float* pos  = (const float*)d_in[1];
    const float* zero = (const float*)d_in[2];
    const float* neg  = (const float*)d_in[3];
    float* out = (float*)d_out;

    unsigned short* Tm = (unsigned short*)d_ws;                    // 32 MiB
    unsigned short* xT = Tm + (size_t)NSEQ * NSEQ;                 // 32 MiB

    build_T<<<dim3(NSEQ * NSEQ / 8 / 256), 256, 0, stream>>>(pos, zero, neg, Tm);
    transpose_x<<<dim3(NSEQ / 64, DDIM / 64, NB), 256, 0, stream>>>(x, xT);
    gemm_toep32n<<<dim3(NSEQ / BMN * (DDIM / BMN) * NB), 512, 0, stream>>>(Tm, xT, out);
}